// Round 2
// baseline (143.777 us; speedup 1.0000x reference)
//
#include <hip/hip_runtime.h>

typedef _Float16 f16;
typedef unsigned short u16;
typedef __attribute__((ext_vector_type(8))) f16 f16x8;
typedef __attribute__((ext_vector_type(4))) f16 f16x4;
typedef __attribute__((ext_vector_type(4))) float floatx4;

#define NPIX 4096
#define KT   128          // keys per attention tile
#define VROW 136          // padded V LDS row (128 keys + 8) in f16

// ---------------------------------------------------------------------------
// Kernel 1: QKV projection as fp16 MFMA GEMM.  (unchanged, known-good)
// grid (64 p-tiles, 6 o-tiles of 64, 4 b), block 256 (4 waves).
// ---------------------------------------------------------------------------
__global__ __launch_bounds__(256) void qkv_mfma(
    const float* __restrict__ x, const float* __restrict__ w,
    f16* __restrict__ qh, f16* __restrict__ kh, f16* __restrict__ vth)
{
    __shared__ f16 wlds[64 * 136];     // [o][c] padded (+8) -> conflict-free frags
    const int tid  = threadIdx.x;
    const int wave = tid >> 6;
    const int lane = tid & 63;
    const int quad = lane >> 4;
    const int l16  = lane & 15;
    const int pbase = blockIdx.x * 64;
    const int y     = blockIdx.y;      // o-tile of 64; type = y>>1
    const int b     = blockIdx.z;

#pragma unroll
    for (int i = 0; i < 8; ++i) {
        int idx = i * 256 + tid;               // 2048 float4
        int o = idx >> 5, ch = idx & 31;
        float4 wv = *(const float4*)(w + (size_t)(y * 64 + o) * 128 + ch * 4);
        f16x4 h; h[0] = (f16)wv.x; h[1] = (f16)wv.y; h[2] = (f16)wv.z; h[3] = (f16)wv.w;
        *(f16x4*)&wlds[o * 136 + ch * 4] = h;
    }
    __syncthreads();

    const float* xb = x + (size_t)b * 128 * NPIX;
    const int type = y >> 1;                   // 0=q 1=k 2=v

    if (type < 2) {
        // ---- C[p][o]: A = X^T (global), B = W (LDS) ----
        const int p_row = pbase + wave * 16 + l16;
        f16x8 af[4];
#pragma unroll
        for (int kc = 0; kc < 4; ++kc) {
            const int c0 = kc * 32 + quad * 8;
#pragma unroll
            for (int j = 0; j < 8; ++j)
                af[kc][j] = (f16)xb[(size_t)(c0 + j) * NPIX + p_row];
        }
        floatx4 acc[4];
#pragma unroll
        for (int n = 0; n < 4; ++n) acc[n] = floatx4{0.f, 0.f, 0.f, 0.f};
#pragma unroll
        for (int n = 0; n < 4; ++n)
#pragma unroll
            for (int kc = 0; kc < 4; ++kc) {
                f16x8 bf = *(const f16x8*)&wlds[(n * 16 + l16) * 136 + kc * 32 + quad * 8];
                acc[n] = __builtin_amdgcn_mfma_f32_16x16x32_f16(af[kc], bf, acc[n], 0, 0, 0);
            }
        const float qs = (type == 0) ? 0.17677669529663687f * 1.4426950408889634f : 1.0f;
        f16* dst = (type == 0) ? qh : kh;
#pragma unroll
        for (int n = 0; n < 4; ++n) {
            const int og   = y * 64 + n * 16 + l16;
            const int head = (og >> 5) & 3;
            const int d    = og & 31;
            f16* base = dst + (size_t)(b * 4 + head) * NPIX * 32;
#pragma unroll
            for (int r = 0; r < 4; ++r) {
                const int p = pbase + wave * 16 + quad * 4 + r;
                base[(size_t)p * 32 + d] = (f16)(acc[n][r] * qs);
            }
        }
    } else {
        // ---- C[o][p]: A = W (LDS), B = X (global) ----
        const int p_col = pbase + wave * 16 + l16;
        f16x8 bf[4];
#pragma unroll
        for (int kc = 0; kc < 4; ++kc) {
            const int c0 = kc * 32 + quad * 8;
#pragma unroll
            for (int j = 0; j < 8; ++j)
                bf[kc][j] = (f16)xb[(size_t)(c0 + j) * NPIX + p_col];
        }
        floatx4 acc[4];
#pragma unroll
        for (int m = 0; m < 4; ++m) acc[m] = floatx4{0.f, 0.f, 0.f, 0.f};
#pragma unroll
        for (int m = 0; m < 4; ++m)
#pragma unroll
            for (int kc = 0; kc < 4; ++kc) {
                f16x8 af = *(const f16x8*)&wlds[(m * 16 + l16) * 136 + kc * 32 + quad * 8];
                acc[m] = __builtin_amdgcn_mfma_f32_16x16x32_f16(af, bf[kc], acc[m], 0, 0, 0);
            }
#pragma unroll
        for (int m = 0; m < 4; ++m)
#pragma unroll
            for (int r = 0; r < 4; ++r) {
                const int og   = y * 64 + m * 16 + quad * 4 + r;
                const int head = (og >> 5) & 3;
                const int d    = og & 31;
                vth[((size_t)(b * 4 + head) * 32 + d) * NPIX + p_col] = (f16)acc[m][r];
            }
    }
}

// ---------------------------------------------------------------------------
// Kernel 2: flash attention via S^T = K*Q^T — baseline structure + key-split.
// v3: block owns 64 q; wave w = (qgrp = w&1, khalf = w>>1). Each wave walks
// its key-half (2048 keys, 16 tiles); fixed-max softmax makes the cross-half
// combine purely additive (oacc + per-lane lsum), done once via LDS overlay.
// grid (64 q-blocks of 64, 16 bh) = 1024 blocks -> 4 blocks/CU = 4 waves/SIMD
// (was 2): the inter-wave phase overlap the lockstep 2-wave schedule lacked.
// Baseline inner loop kept verbatim: single-buffer, 2 barriers/kt, VALU lsum,
// no setprio, klds rows 32 f16 (the v2 "fixes" all measured neutral/negative).
// ---------------------------------------------------------------------------
__global__ __launch_bounds__(256, 4) void attn_kernel(
    const f16* __restrict__ qh, const f16* __restrict__ kh,
    const f16* __restrict__ vth, f16* __restrict__ att)
{
    __shared__ f16 klds[2][KT * 32];     // [khalf][key][d]  2 x 8 KB
    __shared__ f16 vlds[2][32 * VROW];   // [khalf][d][key]  2 x 8.5 KB (padded)

    const int tid  = threadIdx.x;
    const int wave = tid >> 6;
    const int lane = tid & 63;
    const int quad = lane >> 4;
    const int l16  = lane & 15;
    const int bh   = blockIdx.y;
    const int qgrp  = wave & 1;          // which 32-q group of the block's 64
    const int khalf = wave >> 1;         // which 2048-key half
    const int qbase = blockIdx.x * 64 + qgrp * 32;

    const f16* kb = kh + (size_t)bh * NPIX * 32;
    const f16* vb = vth + (size_t)bh * 32 * NPIX;

    // Q B-frags (B[k=d][n=q]): two 16-q subtiles
    f16x8 qB[2];
#pragma unroll
    for (int h = 0; h < 2; ++h)
        qB[h] = *(const f16x8*)(qh + ((size_t)bh * NPIX + qbase + h * 16 + l16) * 32 + quad * 8);

    floatx4 oacc[2][2];
#pragma unroll
    for (int h = 0; h < 2; ++h)
#pragma unroll
        for (int dh = 0; dh < 2; ++dh) oacc[h][dh] = floatx4{0.f, 0.f, 0.f, 0.f};
    float lsum[2] = {0.f, 0.f};

    for (int kt = 0; kt < 16; ++kt) {
        __syncthreads();
        // stage BOTH key-halves' tiles (slot s <- global tile s*16 + kt)
#pragma unroll
        for (int s = 0; s < 2; ++s) {
            const int4* src = (const int4*)(kb + (size_t)(s * 16 + kt) * KT * 32);
            ((int4*)klds[s])[tid]       = src[tid];
            ((int4*)klds[s])[tid + 256] = src[tid + 256];
        }
#pragma unroll
        for (int s = 0; s < 2; ++s) {
            const int r  = tid >> 3;
            const int cc = (tid & 7) * 2;
            const int4* vsrc = (const int4*)(vb + (size_t)r * NPIX + (s * 16 + kt) * KT + cc * 8);
            int4 v0 = vsrc[0], v1 = vsrc[1];
            int4* vdst = (int4*)(vlds[s] + r * VROW + cc * 8);
            vdst[0] = v0; vdst[1] = v1;
        }
        __syncthreads();

        // cache K A-frags (A[m=key][k=d]) and V B-frags (B[k=key][n=d]) from MY half
        f16x8 kf[8];
#pragma unroll
        for (int t = 0; t < 8; ++t)
            kf[t] = *(const f16x8*)&klds[khalf][(t * 16 + l16) * 32 + quad * 8];
        f16x4 vf[8][2];
#pragma unroll
        for (int c = 0; c < 8; ++c)
#pragma unroll
            for (int dh = 0; dh < 2; ++dh)
                vf[c][dh] = *(const f16x4*)&vlds[khalf][(dh * 16 + l16) * VROW + c * 16 + quad * 4];

#pragma unroll
        for (int h = 0; h < 2; ++h) {
            // S^T: D[key][q], 8 subtiles of 16 keys, full K=32 reduction
            floatx4 st[8];
#pragma unroll
            for (int t = 0; t < 8; ++t) {
                floatx4 z = {0.f, 0.f, 0.f, 0.f};
                st[t] = __builtin_amdgcn_mfma_f32_16x16x32_f16(kf[t], qB[h], z, 0, 0, 0);
            }
            // exp2 in-lane -> P A-frags; accumulate row sums (per q = l16)
            f16x4 pf[8];
            float ls = 0.f;
#pragma unroll
            for (int c = 0; c < 8; ++c)
#pragma unroll
                for (int r = 0; r < 4; ++r) {
                    float e = __builtin_amdgcn_exp2f(st[c][r]);
                    ls += e;
                    pf[c][r] = (f16)e;
                }
            lsum[h] += ls;
            // PV: O[q][d] += P[q][key] * V[key][d], K=16 chunks
#pragma unroll
            for (int c = 0; c < 8; ++c) {
                oacc[h][0] = __builtin_amdgcn_mfma_f32_16x16x16f16(pf[c], vf[c][0], oacc[h][0], 0, 0, 0);
                oacc[h][1] = __builtin_amdgcn_mfma_f32_16x16x16f16(pf[c], vf[c][1], oacc[h][1], 0, 0, 0);
            }
        }
    }

    // ---- cross-half combine: khalf=1 publishes unnormalized partials via LDS
    // (overlaid on vlds; barrier guarantees all tile reads are done), khalf=0
    // waves add them and run the baseline epilogue. Stride 19 floats -> no
    // systematic bank aliasing. 2*64*19*4 = 9.7 KB << 34 KB available.
    __syncthreads();
    float* comb = (float*)&vlds[0][0];
    const int ci = (qgrp * 64 + lane) * 19;
    if (khalf == 1) {
        float* p = comb + ci;
#pragma unroll
        for (int h = 0; h < 2; ++h)
#pragma unroll
            for (int dh = 0; dh < 2; ++dh)
#pragma unroll
                for (int r = 0; r < 4; ++r)
                    p[h * 8 + dh * 4 + r] = oacc[h][dh][r];
        p[16] = lsum[0];
        p[17] = lsum[1];
    }
    __syncthreads();
    if (khalf == 1) return;
    {
        const float* p = comb + ci;
#pragma unroll
        for (int h = 0; h < 2; ++h)
#pragma unroll
            for (int dh = 0; dh < 2; ++dh)
#pragma unroll
                for (int r = 0; r < 4; ++r)
                    oacc[h][dh][r] += p[h * 8 + dh * 4 + r];
        lsum[0] += p[16];
        lsum[1] += p[17];
    }

    // epilogue (baseline): reduce lsum across quads (q lives in l16), divide, store
#pragma unroll
    for (int h = 0; h < 2; ++h) {
        float l = lsum[h];
        l += __shfl_xor(l, 16);
        l += __shfl_xor(l, 32);
        const float inv = 1.0f / l;            // valid per q = l16
#pragma unroll
        for (int r = 0; r < 4; ++r) {
            const float invr = __shfl(inv, quad * 4 + r);   // inv for q-row quad*4+r
            const int q = qbase + h * 16 + quad * 4 + r;
            f16* ob = att + ((size_t)bh * NPIX + q) * 32;
            ob[l16]      = (f16)(oacc[h][0][r] * invr);
            ob[16 + l16] = (f16)(oacc[h][1][r] * invr);
        }
    }
}

// ---------------------------------------------------------------------------
// Kernel 3: output projection as fp16 MFMA GEMM.  (reverted to round-0 form)
// C[o][p] = Wp[o][c] * att^T[c][p] + bias; att[bh][p][32] IS the natural
// B-fragment layout (16B contiguous per lane). Stores coalesced fp32.
// grid (64 p-tiles, 4 b), block 256 (4 waves).
// ---------------------------------------------------------------------------
__global__ __launch_bounds__(256) void proj_mfma(
    const f16* __restrict__ att, const float* __restrict__ wp,
    const float* __restrict__ bp, float* __restrict__ out)
{
    __shared__ f16 wplds[128 * 136];   // [o][c] padded, 34.8 KB
    __shared__ float bplds[128];
    const int tid  = threadIdx.x;
    const int wave = tid >> 6;
    const int lane = tid & 63;
    const int quad = lane >> 4;
    const int l16  = lane & 15;
    const int pbase = blockIdx.x * 64;
    const int b     = blockIdx.y;

    if (tid < 128) bplds[tid] = bp[tid];
#pragma unroll
    for (int i = 0; i < 16; ++i) {
        int idx = i * 256 + tid;               // 4096 float4 = 128*128 floats
        int o = idx >> 5, ch = idx & 31;
        float4 wv = *(const float4*)(wp + (size_t)o * 128 + ch * 4);
        f16x4 h; h[0] = (f16)wv.x; h[1] = (f16)wv.y; h[2] = (f16)wv.z; h[3] = (f16)wv.w;
        *(f16x4*)&wplds[o * 136 + ch * 4] = h;
    }
    __syncthreads();

    const f16* ab = att + (size_t)b * 4 * NPIX * 32;
    const int p_col = pbase + wave * 16 + l16;
    f16x8 bf[4];
#pragma unroll
    for (int kc = 0; kc < 4; ++kc)
        bf[kc] = *(const f16x8*)(ab + ((size_t)kc * NPIX + p_col) * 32 + quad * 8);

    floatx4 acc[8];
#pragma unroll
    for (int m = 0; m < 8; ++m) acc[m] = floatx4{0.f, 0.f, 0.f, 0.f};
#pragma unroll
    for (int m = 0; m < 8; ++m)
#pragma unroll
        for (int kc = 0; kc < 4; ++kc) {
            f16x8 af = *(const f16x8*)&wplds[(m * 16 + l16) * 136 + kc * 32 + quad * 8];
            acc[m] = __builtin_amdgcn_mfma_f32_16x16x32_f16(af, bf[kc], acc[m], 0, 0, 0);
        }

#pragma unroll
    for (int m = 0; m < 8; ++m)
#pragma unroll
        for (int r = 0; r < 4; ++r) {
            const int o = m * 16 + quad * 4 + r;
            out[((size_t)b * 128 + o) * NPIX + p_col] = acc[m][r] + bplds[o];
        }
}

// ---------------------------------------------------------------------------
extern "C" void kernel_launch(void* const* d_in, const int* in_sizes, int n_in,
                              void* d_out, int out_size, void* d_ws, size_t ws_size,
                              hipStream_t stream)
{
    const float* x      = (const float*)d_in[0];
    const float* w_qkv  = (const float*)d_in[1];
    const float* w_proj = (const float*)d_in[2];
    const float* b_proj = (const float*)d_in[3];
    float* out = (float*)d_out;

    char* ws = (char*)d_ws;
    f16* qh  = (f16*)(ws);                // 16*4096*32 f16 = 4 MB, pre-scaled
    f16* kh  = (f16*)(ws + (4u << 20));   // 4 MB [bh][p][32]
    f16* vth = (f16*)(ws + (8u << 20));   // 4 MB [bh][d][p]
    f16* att = (f16*)(ws + (12u << 20));  // 4 MB [bh][p][32]

    qkv_mfma<<<dim3(64, 6, 4), 256, 0, stream>>>(x, w_qkv, qh, kh, vth);
    attn_kernel<<<dim3(64, 16, 1), 256, 0, stream>>>(qh, kh, vth, att);
    proj_mfma<<<dim3(64, 4, 1), 256, 0, stream>>>(att, w_proj, b_proj, out);
}